// Round 15
// baseline (287.085 us; speedup 1.0000x reference)
//
#include <hip/hip_runtime.h>

#define B_ 8
#define N_ 1024
#define C_ 768
#define H_ 12
#define BH_ 96            // B*H
#define D2_ 128           // 2*D
#define C2_ 1536          // 2*C

static constexpr float SCALE_LOG2 = 0.125f * 1.4426950408889634f; // D^-0.5 * log2(e)
static constexpr float OUT_SCALE  = 0.8f;   // 1 - LAMBDA_INIT
static constexpr float EPS_       = 1e-5f;

using bf16x8 = __attribute__((ext_vector_type(8))) short;
using f32x4  = __attribute__((ext_vector_type(4))) float;
typedef unsigned short ushort_t;
typedef unsigned int   uint_t;

#define GLOAD16(g, l) __builtin_amdgcn_global_load_lds( \
    (const __attribute__((address_space(1))) void*)(g), \
    (__attribute__((address_space(3))) void*)(l), 16, 0, 0)

__device__ __forceinline__ ushort_t f2bf(float f) {
    uint_t u = __float_as_uint(f);
    u = (u + 0x7FFFu + ((u >> 16) & 1u)) >> 16;
    return (ushort_t)u;
}
// HW packed f32->bf16 (RNE, same as f2bf)
__device__ __forceinline__ uint_t cvtpk(float a, float b) {
    uint_t r;
    asm("v_cvt_pk_bf16_f32 %0, %1, %2" : "=v"(r) : "v"(a), "v"(b));
    return r;
}

// ---------------- fp32 -> bf16 convert (x) ----------------
__global__ __launch_bounds__(256) void cvt_bf16_kernel(const float* __restrict__ in,
                                                       ushort_t* __restrict__ out, int n4) {
    for (int i = blockIdx.x * 256 + threadIdx.x; i < n4; i += gridDim.x * 256) {
        float4 v = reinterpret_cast<const float4*>(in)[i];
        ushort4 o;
        o.x = f2bf(v.x); o.y = f2bf(v.y); o.z = f2bf(v.z); o.w = f2bf(v.w);
        reinterpret_cast<ushort4*>(out)[i] = o;
    }
}

// ---------------- all four W (KxN f32) -> Wt (NxK bf16) in ONE launch ----------------
__global__ __launch_bounds__(256)
void transpose_cvt4_kernel(const float* __restrict__ Wq, const float* __restrict__ Wk,
                           const float* __restrict__ Wv, const float* __restrict__ Wp,
                           ushort_t* __restrict__ wqt, ushort_t* __restrict__ wkt,
                           ushort_t* __restrict__ wvt, ushort_t* __restrict__ wpt) {
    __shared__ float t[32][33];
    const float* W; ushort_t* Wt; int K, Nn;
    switch (blockIdx.z) {
        case 0:  W = Wq; Wt = wqt; K = C_;  Nn = C2_; break;
        case 1:  W = Wk; Wt = wkt; K = C_;  Nn = C2_; break;
        case 2:  W = Wv; Wt = wvt; K = C_;  Nn = C2_; break;
        default: W = Wp; Wt = wpt; K = C2_; Nn = C_;  break;
    }
    if ((int)blockIdx.x * 32 >= Nn || (int)blockIdx.y * 32 >= K) return;  // block-uniform
    const int n0 = blockIdx.x * 32, k0 = blockIdx.y * 32;
    const int tx = threadIdx.x & 31, ty = threadIdx.x >> 5;
    #pragma unroll
    for (int r = ty; r < 32; r += 8)
        t[r][tx] = W[(size_t)(k0 + r) * Nn + n0 + tx];
    __syncthreads();
    #pragma unroll
    for (int r = ty; r < 32; r += 8)
        Wt[(size_t)(n0 + r) * K + k0 + tx] = f2bf(t[tx][r]);
}

// ---------------- V (bh,1024,128) -> Vt (bh,128,1024), bf16 ----------------
__global__ __launch_bounds__(256) void transpose_v_kernel(const ushort_t* __restrict__ V,
                                                          ushort_t* __restrict__ Vt) {
    __shared__ ushort_t t[64][65];
    const int bh = blockIdx.z;
    const int d0 = blockIdx.x * 64, n0 = blockIdx.y * 64;
    const int tx = threadIdx.x & 63, ty = threadIdx.x >> 6;
    const ushort_t* src = V + (size_t)bh * N_ * D2_;
    ushort_t* dst = Vt + (size_t)bh * N_ * D2_;
    #pragma unroll
    for (int r = ty; r < 64; r += 4)
        t[r][tx] = src[(size_t)(n0 + r) * D2_ + d0 + tx];
    __syncthreads();
    #pragma unroll
    for (int r = ty; r < 64; r += 4)
        dst[(size_t)(d0 + r) * N_ + n0 + tx] = t[tx][r];
}

// ---------------- bf16 GEMM: C = A(MxK) @ Bt(NxK)^T ----------------
// REMAP=1: fused QKV (Nn=4608, Bt=[Wq;Wk;Wv] rows); writes bf16 to the three
//          consecutive (B*H, N_, 128) q/k/v buffers; q (p==0) scaled by qscale.
// REMAP=0: f32 + bias to (M, Nn).
// XCD-chunked blockIdx swizzle (linear bijection; nwg % 8 == 0 for both call
// sites: 2304 and 384). Output-invariant: per-block work depends only on
// (m0,n0), and this kernel's outputs are 3x-reproduced deterministic.
template <int REMAP>
__global__ __launch_bounds__(256)
void gemm_bf16_kernel(const ushort_t* __restrict__ A, const ushort_t* __restrict__ Bt,
                      const float* __restrict__ bias, void* __restrict__ dst,
                      int M, int Nn, int K, float qscale)
{
    __shared__ __align__(16) char As[8192];
    __shared__ __align__(16) char Bs[8192];
    const int tid = threadIdx.x;
    const int wv = tid >> 6, lane = tid & 63;
    const int l15 = lane & 15, lg = lane >> 4;

    // XCD swizzle on the linear block index
    const int gx = Nn >> 7;                       // Nn/128
    const int nwg = gx * (M >> 7);
    const int chunk = nwg >> 3;                   // nwg/8 (exact)
    const int lin = blockIdx.y * gx + blockIdx.x;
    const int lin2 = (lin & 7) * chunk + (lin >> 3);
    const int m0 = (lin2 / gx) * 128, n0 = (lin2 % gx) * 128;

    const int wm = (wv >> 1) * 64, wn = (wv & 1) * 64;

    f32x4 acc[4][4] = {};
    const size_t ldb = (size_t)K * 2;   // bytes per row of A and Bt

    for (int k0 = 0; k0 < K; k0 += 32) {
        __syncthreads();
        #pragma unroll
        for (int q = 0; q < 2; ++q) {
            const int o = wv * 2048 + q * 1024 + lane * 16;
            const int sw = (o & 63) ^ ((((o >> 7) & 3)) << 4);
            const char* sa = (const char*)A + (size_t)(m0 + (o >> 6)) * ldb + k0 * 2 + sw;
            const char* sb = (const char*)Bt + (size_t)(n0 + (o >> 6)) * ldb + k0 * 2 + sw;
            GLOAD16(sa, As + wv * 2048 + q * 1024);
            GLOAD16(sb, Bs + wv * 2048 + q * 1024);
        }
        __syncthreads();
        bf16x8 af[4], bfr[4];
        #pragma unroll
        for (int i = 0; i < 4; ++i) {
            const int ra = wm + i * 16 + l15;
            af[i] = *(const bf16x8*)(As + ra * 64 + ((lg ^ ((ra >> 1) & 3)) << 4));
            const int rb = wn + i * 16 + l15;
            bfr[i] = *(const bf16x8*)(Bs + rb * 64 + ((lg ^ ((rb >> 1) & 3)) << 4));
        }
        #pragma unroll
        for (int i = 0; i < 4; ++i)
            #pragma unroll
            for (int j = 0; j < 4; ++j)
                acc[i][j] = __builtin_amdgcn_mfma_f32_16x16x32_bf16(af[i], bfr[j], acc[i][j], 0, 0, 0);
    }

    if (REMAP) {
        const int p = n0 / C2_;                       // constant per block
        const float os = (p == 0) ? qscale : 1.0f;    // *1.0f is exact identity
        ushort_t* D = (ushort_t*)dst + (size_t)p * ((size_t)BH_ * N_ * D2_);
        const int nb = n0 - p * C2_;
        #pragma unroll
        for (int i = 0; i < 4; ++i)
            #pragma unroll
            for (int r = 0; r < 4; ++r) {
                const int m = m0 + wm + i * 16 + lg * 4 + r;
                const int b = m >> 10, ns = m & 1023;
                #pragma unroll
                for (int j = 0; j < 4; ++j) {
                    const int n = nb + wn + j * 16 + l15;
                    const int h = n >> 7, d = n & 127;
                    D[(((size_t)(b * H_ + h)) * N_ + ns) * D2_ + d] = f2bf(acc[i][j][r] * os);
                }
            }
    } else {
        float* D = (float*)dst;
        #pragma unroll
        for (int i = 0; i < 4; ++i)
            #pragma unroll
            for (int r = 0; r < 4; ++r) {
                const int m = m0 + wm + i * 16 + lg * 4 + r;
                #pragma unroll
                for (int j = 0; j < 4; ++j) {
                    const int n = n0 + wn + j * 16 + l15;
                    D[(size_t)m * Nn + n] = acc[i][j][r] + bias[n];
                }
            }
    }
}

// ---------------- differential flash attention + LayerNorm, bf16 MFMA ----------------
// Block = 4 waves, 64 q-rows of one (b,h). S^T = K*Q^T so softmax rows are lane-local.
// Deterministic reg-staged dbuf. BYTE-EXACT R13 artifact (verified passing 3x at
// absmax 0.0234375; six attempted inner-loop edits all corrupted — do not touch).
__global__ __launch_bounds__(256)
void attn_kernel(const ushort_t* __restrict__ qb, const ushort_t* __restrict__ kb,
                 const ushort_t* __restrict__ vt, const float* __restrict__ lamp,
                 const float* __restrict__ gamma, const float* __restrict__ beta,
                 ushort_t* __restrict__ Y)
{
    __shared__ __align__(16) char Ks[2][8192];
    __shared__ __align__(16) char Vs[2][8192];
    __shared__ __align__(16) ushort_t Ps[4][2][16 * 40];

    const int tid = threadIdx.x;
    const int wv = tid >> 6, lane = tid & 63;
    const int l15 = lane & 15, lg = lane >> 4;
    // XCD swizzle (bijection on [0,1536)): all 16 q-tiles of one (b,h) on one XCD
    const int swz = (blockIdx.x & 7) * 192 + (blockIdx.x >> 3);
    const int bh = swz >> 4;
    const int qt = swz & 15;

    const char* kbase = (const char*)kb + (size_t)bh * (N_ * D2_ * 2);
    const char* vbase = (const char*)vt + (size_t)bh * (N_ * D2_ * 2);

    // staging indices: K tile = 32 rows x 256B; V tile = 128 d-rows x 64B
    const int krow = tid >> 4, kcol = tid & 15;
    const int kg0 = tid * 16, kg1 = kg0 + 4096;
    const int ksw = (kcol ^ (krow & 7)) << 4;
    const int kw0 = krow * 256 + ksw;
    const int kw1 = (krow + 16) * 256 + ksw;
    const int vdr = tid >> 2, vpart = tid & 3;
    const size_t vg0 = (size_t)vdr * (N_ * 2) + vpart * 16;
    const size_t vg1 = (size_t)(vdr + 64) * (N_ * 2) + vpart * 16;
    const int vsw = (vpart ^ ((vdr >> 1) & 3)) << 4;
    const int vw0 = vdr * 64 + vsw;
    const int vw1 = (vdr + 64) * 64 + vsw;

    // Q fragments (B-operand); Q pre-scaled by D^-0.5*log2e at projection
    const int qrow = qt * 64 + wv * 16 + l15;
    const ushort_t* qptr = qb + (size_t)bh * N_ * D2_ + (size_t)qrow * D2_;
    bf16x8 Qf[4];
    #pragma unroll
    for (int c = 0; c < 4; ++c)
        Qf[c] = *(const bf16x8*)(qptr + c * 32 + lg * 8);

    f32x4 O1[8] = {}, O2[8] = {};
    float l1p = 0.f, l2p = 0.f;

    // prologue: stage tile 0 through registers
    {
        uint4 a = *(const uint4*)(kbase + kg0);
        uint4 b = *(const uint4*)(kbase + kg1);
        uint4 c = *(const uint4*)(vbase + vg0);
        uint4 d = *(const uint4*)(vbase + vg1);
        *(uint4*)(Ks[0] + kw0) = a; *(uint4*)(Ks[0] + kw1) = b;
        *(uint4*)(Vs[0] + vw0) = c; *(uint4*)(Vs[0] + vw1) = d;
    }
    __syncthreads();
    int cur = 0;

    for (int t = 0; t < 32; ++t) {
        // issue next tile's global loads early (latency hides under compute)
        uint4 nk0, nk1, nv0, nv1;
        if (t < 31) {
            nk0 = *(const uint4*)(kbase + (t + 1) * 8192 + kg0);
            nk1 = *(const uint4*)(kbase + (t + 1) * 8192 + kg1);
            nv0 = *(const uint4*)(vbase + vg0 + (t + 1) * 64);
            nv1 = *(const uint4*)(vbase + vg1 + (t + 1) * 64);
        }

        const char* Kc = Ks[cur];
        const char* Vc = Vs[cur];

        // S^T = K * Q^T ; split1 = d 0..63 (chunks 0,1), split2 = d 64..127
        f32x4 s1[2], s2[2];
        #pragma unroll
        for (int u = 0; u < 2; ++u) {
            const int row = u * 16 + l15;
            const char* kp = Kc + row * 256;
            bf16x8 k0 = *(const bf16x8*)(kp + (((0  + lg) ^ (row & 7)) << 4));
            bf16x8 k1 = *(const bf16x8*)(kp + (((4  + lg) ^ (row & 7)) << 4));
            bf16x8 k2 = *(const bf16x8*)(kp + (((8  + lg) ^ (row & 7)) << 4));
            bf16x8 k3 = *(const bf16x8*)(kp + (((12 + lg) ^ (row & 7)) << 4));
            f32x4 z = {0.f, 0.f, 0.f, 0.f};
            s1[u] = __builtin_amdgcn_mfma_f32_16x16x32_bf16(k0, Qf[0], z, 0, 0, 0);
            s1[u] = __builtin_amdgcn_mfma_f32_16x16x32_bf16(k1, Qf[1], s1[u], 0, 0, 0);
            s2[u] = __builtin_amdgcn_mfma_f32_16x16x32_bf16(k2, Qf[2], z, 0, 0, 0);
            s2[u] = __builtin_amdgcn_mfma_f32_16x16x32_bf16(k3, Qf[3], s2[u], 0, 0, 0);
        }

        // exp2 (scores already in log2 units) + HW packed bf16 convert
        float lp1 = 0.f, lp2 = 0.f;
        #pragma unroll
        for (int u = 0; u < 2; ++u) {
            const uint_t base = (uint_t)(l15 * 40 + u * 16 + lg * 4) >> 1;
            float a0 = exp2f(s1[u][0]), a1 = exp2f(s1[u][1]);
            float a2 = exp2f(s1[u][2]), a3 = exp2f(s1[u][3]);
            lp1 += (a0 + a1) + (a2 + a3);
            ((uint_t*)Ps[wv][0])[base]     = cvtpk(a0, a1);
            ((uint_t*)Ps[wv][0])[base + 1] = cvtpk(a2, a3);
            float b0 = exp2f(s2[u][0]), b1 = exp2f(s2[u][1]);
            float b2 = exp2f(s2[u][2]), b3 = exp2f(s2[u][3]);
            lp2 += (b0 + b1) + (b2 + b3);
            ((uint_t*)Ps[wv][1])[base]     = cvtpk(b0, b1);
            ((uint_t*)Ps[wv][1])[base + 1] = cvtpk(b2, b3);
        }
        l1p += lp1; l2p += lp2;

        bf16x8 pa1 = *(const bf16x8*)&Ps[wv][0][l15 * 40 + lg * 8];
        bf16x8 pa2 = *(const bf16x8*)&Ps[wv][1][l15 * 40 + lg * 8];

        #pragma unroll
        for (int c = 0; c < 8; ++c) {
            const int dr = c * 16 + l15;
            bf16x8 vf = *(const bf16x8*)(Vc + dr * 64 + ((lg ^ ((dr >> 1) & 3)) << 4));
            O1[c] = __builtin_amdgcn_mfma_f32_16x16x32_bf16(pa1, vf, O1[c], 0, 0, 0);
            O2[c] = __builtin_amdgcn_mfma_f32_16x16x32_bf16(pa2, vf, O2[c], 0, 0, 0);
        }

        // write next tile into the other buffer (no aliasing with this tile's reads)
        if (t < 31) {
            char* Kn = Ks[cur ^ 1];
            char* Vn = Vs[cur ^ 1];
            *(uint4*)(Kn + kw0) = nk0; *(uint4*)(Kn + kw1) = nk1;
            *(uint4*)(Vn + vw0) = nv0; *(uint4*)(Vn + vw1) = nv1;
        }
        __syncthreads();
        cur ^= 1;
    }

    // ---- epilogue: normalize, differential combine, LayerNorm, write Y ----
    float l1 = l1p + __shfl_xor(l1p, 16); l1 += __shfl_xor(l1, 32);
    float l2 = l2p + __shfl_xor(l2p, 16); l2 += __shfl_xor(l2, 32);
    const float lam = lamp[0];
    float i1[4], i2[4];
    #pragma unroll
    for (int r = 0; r < 4; ++r) {
        i1[r] = 1.f / __shfl(l1, lg * 4 + r);
        i2[r] = lam / __shfl(l2, lg * 4 + r);
    }
    float su[4] = {0.f, 0.f, 0.f, 0.f}, sq[4] = {0.f, 0.f, 0.f, 0.f};
    float ov[8][4];
    #pragma unroll
    for (int c = 0; c < 8; ++c)
        #pragma unroll
        for (int r = 0; r < 4; ++r) {
            const float v = O1[c][r] * i1[r] - O2[c][r] * i2[r];
            ov[c][r] = v; su[r] += v; sq[r] += v * v;
        }
    #pragma unroll
    for (int r = 0; r < 4; ++r) {
        #pragma unroll
        for (int msk = 1; msk <= 8; msk <<= 1) {
            su[r] += __shfl_xor(su[r], msk);
            sq[r] += __shfl_xor(sq[r], msk);
        }
    }
    float gv[8], bv[8];
    #pragma unroll
    for (int c = 0; c < 8; ++c) { gv[c] = gamma[c * 16 + l15]; bv[c] = beta[c * 16 + l15]; }

    const int b = bh / H_, h = bh - (bh / H_) * H_;
    #pragma unroll
    for (int r = 0; r < 4; ++r) {
        const float mu = su[r] * (1.f / 128.f);
        const float var = sq[r] * (1.f / 128.f) - mu * mu;
        const float rstd = rsqrtf(var + EPS_);
        const int n = qt * 64 + wv * 16 + lg * 4 + r;
        ushort_t* yrow = Y + ((size_t)(b * N_ + n)) * C2_ + h * D2_;
        #pragma unroll
        for (int c = 0; c < 8; ++c) {
            const int d = c * 16 + l15;
            const float val = ((ov[c][r] - mu) * rstd * gv[c] + bv[c]) * OUT_SCALE;
            yrow[d] = f2bf(val);
        }
    }
}

extern "C" void kernel_launch(void* const* d_in, const int* in_sizes, int n_in,
                              void* d_out, int out_size, void* d_ws, size_t ws_size,
                              hipStream_t stream) {
    const float* x     = (const float*)d_in[0];
    const float* Wq    = (const float*)d_in[1];
    const float* Wk    = (const float*)d_in[2];
    const float* Wv    = (const float*)d_in[3];
    const float* lam   = (const float*)d_in[4];
    const float* gamma = (const float*)d_in[5];
    const float* beta  = (const float*)d_in[6];
    const float* Wp    = (const float*)d_in[7];
    const float* bp    = (const float*)d_in[8];
    float* out = (float*)d_out;

    // workspace layout (bytes)
    char* w = (char*)d_ws;
    ushort_t* xb  = (ushort_t*)w;                 w += (size_t)B_ * N_ * C_ * 2;        // 12.6MB
    ushort_t* wqt = (ushort_t*)w;                 w += (size_t)C2_ * C_ * 2;            // 2.36MB (x3, consecutive)
    ushort_t* wkt = (ushort_t*)w;                 w += (size_t)C2_ * C_ * 2;
    ushort_t* wvt = (ushort_t*)w;                 w += (size_t)C2_ * C_ * 2;
    ushort_t* wpt = (ushort_t*)w;                 w += (size_t)C_ * C2_ * 2;
    ushort_t* qbuf = (ushort_t*)w;                w += (size_t)BH_ * N_ * D2_ * 2;      // 25.2MB (q,k,v consecutive)
    ushort_t* kbuf = (ushort_t*)w;                w += (size_t)BH_ * N_ * D2_ * 2;
    ushort_t* vbuf = (ushort_t*)w;                w += (size_t)BH_ * N_ * D2_ * 2;
    ushort_t* vtb  = (ushort_t*)w;                w += (size_t)BH_ * N_ * D2_ * 2;
    ushort_t* Yb   = (ushort_t*)w;                w += (size_t)B_ * N_ * C2_ * 2;       // 25.2MB

    const int M = B_ * N_;   // 8192

    // convert x to bf16
    cvt_bf16_kernel<<<2048, 256, 0, stream>>>(x, xb, (B_ * N_ * C_) / 4);
    // all four weight transposes in one launch
    transpose_cvt4_kernel<<<dim3(48, 48, 4), 256, 0, stream>>>(Wq, Wk, Wv, Wp,
                                                               wqt, wkt, wvt, wpt);

    // fused QKV projection: one GEMM over [Wq;Wk;Wv] (N=4608); Q pre-scaled
    {
        dim3 grid((3 * C2_) / 128, M / 128);
        gemm_bf16_kernel<1><<<grid, 256, 0, stream>>>(xb, wqt, nullptr, qbuf,
                                                      M, 3 * C2_, C_, SCALE_LOG2);
    }
    (void)kbuf;
    // V -> V^T per head
    transpose_v_kernel<<<dim3(D2_ / 64, N_ / 64, BH_), 256, 0, stream>>>(vbuf, vtb);

    // differential attention + LN -> Y (B,N,2C) bf16
    attn_kernel<<<dim3(BH_ * (N_ / 64)), 256, 0, stream>>>(qbuf, kbuf, vtb, lam, gamma, beta, Yb);

    // output projection: out = Y @ Wp + bp (f32)
    {
        dim3 grid(C_ / 128, M / 128);
        gemm_bf16_kernel<0><<<grid, 256, 0, stream>>>(Yb, wpt, bp, out, M, C_, C2_, 1.0f);
    }
}

// Round 16
// 281.461 us; speedup vs baseline: 1.0200x; 1.0200x over previous
//
#include <hip/hip_runtime.h>

#define B_ 8
#define N_ 1024
#define C_ 768
#define H_ 12
#define BH_ 96            // B*H
#define D2_ 128           // 2*D
#define C2_ 1536          // 2*C

static constexpr float SCALE_LOG2 = 0.125f * 1.4426950408889634f; // D^-0.5 * log2(e)
static constexpr float OUT_SCALE  = 0.8f;   // 1 - LAMBDA_INIT
static constexpr float EPS_       = 1e-5f;

using bf16x8 = __attribute__((ext_vector_type(8))) short;
using f32x4  = __attribute__((ext_vector_type(4))) float;
typedef unsigned short ushort_t;
typedef unsigned int   uint_t;

#define GLOAD16(g, l) __builtin_amdgcn_global_load_lds( \
    (const __attribute__((address_space(1))) void*)(g), \
    (__attribute__((address_space(3))) void*)(l), 16, 0, 0)

__device__ __forceinline__ ushort_t f2bf(float f) {
    uint_t u = __float_as_uint(f);
    u = (u + 0x7FFFu + ((u >> 16) & 1u)) >> 16;
    return (ushort_t)u;
}
// HW packed f32->bf16 (RNE, same as f2bf)
__device__ __forceinline__ uint_t cvtpk(float a, float b) {
    uint_t r;
    asm("v_cvt_pk_bf16_f32 %0, %1, %2" : "=v"(r) : "v"(a), "v"(b));
    return r;
}

// ---------------- fp32 -> bf16 convert (x) ----------------
__global__ __launch_bounds__(256) void cvt_bf16_kernel(const float* __restrict__ in,
                                                       ushort_t* __restrict__ out, int n4) {
    for (int i = blockIdx.x * 256 + threadIdx.x; i < n4; i += gridDim.x * 256) {
        float4 v = reinterpret_cast<const float4*>(in)[i];
        ushort4 o;
        o.x = f2bf(v.x); o.y = f2bf(v.y); o.z = f2bf(v.z); o.w = f2bf(v.w);
        reinterpret_cast<ushort4*>(out)[i] = o;
    }
}

// ---------------- all four W (KxN f32) -> Wt (NxK bf16) in ONE launch ----------------
__global__ __launch_bounds__(256)
void transpose_cvt4_kernel(const float* __restrict__ Wq, const float* __restrict__ Wk,
                           const float* __restrict__ Wv, const float* __restrict__ Wp,
                           ushort_t* __restrict__ wqt, ushort_t* __restrict__ wkt,
                           ushort_t* __restrict__ wvt, ushort_t* __restrict__ wpt) {
    __shared__ float t[32][33];
    const float* W; ushort_t* Wt; int K, Nn;
    switch (blockIdx.z) {
        case 0:  W = Wq; Wt = wqt; K = C_;  Nn = C2_; break;
        case 1:  W = Wk; Wt = wkt; K = C_;  Nn = C2_; break;
        case 2:  W = Wv; Wt = wvt; K = C_;  Nn = C2_; break;
        default: W = Wp; Wt = wpt; K = C2_; Nn = C_;  break;
    }
    if ((int)blockIdx.x * 32 >= Nn || (int)blockIdx.y * 32 >= K) return;  // block-uniform
    const int n0 = blockIdx.x * 32, k0 = blockIdx.y * 32;
    const int tx = threadIdx.x & 31, ty = threadIdx.x >> 5;
    #pragma unroll
    for (int r = ty; r < 32; r += 8)
        t[r][tx] = W[(size_t)(k0 + r) * Nn + n0 + tx];
    __syncthreads();
    #pragma unroll
    for (int r = ty; r < 32; r += 8)
        Wt[(size_t)(n0 + r) * K + k0 + tx] = f2bf(t[tx][r]);
}

// ---------------- V (bh,1024,128) -> Vt (bh,128,1024), bf16 ----------------
__global__ __launch_bounds__(256) void transpose_v_kernel(const ushort_t* __restrict__ V,
                                                          ushort_t* __restrict__ Vt) {
    __shared__ ushort_t t[64][65];
    const int bh = blockIdx.z;
    const int d0 = blockIdx.x * 64, n0 = blockIdx.y * 64;
    const int tx = threadIdx.x & 63, ty = threadIdx.x >> 6;
    const ushort_t* src = V + (size_t)bh * N_ * D2_;
    ushort_t* dst = Vt + (size_t)bh * N_ * D2_;
    #pragma unroll
    for (int r = ty; r < 64; r += 4)
        t[r][tx] = src[(size_t)(n0 + r) * D2_ + d0 + tx];
    __syncthreads();
    #pragma unroll
    for (int r = ty; r < 64; r += 4)
        dst[(size_t)(d0 + r) * N_ + n0 + tx] = t[tx][r];
}

// ---------------- bf16 GEMM: C = A(MxK) @ Bt(NxK)^T ----------------
// REMAP=1: fused QKV (Nn=4608, Bt=[Wq;Wk;Wv] rows); writes bf16 to the three
//          consecutive (B*H, N_, 128) q/k/v buffers; q (p==0) scaled by qscale.
// REMAP=0: f32 + bias to (M, Nn).
// (No XCD swizzle: R15 measured it neutral-to-negative here — all buffers are
// L3-resident, so there is no HBM re-fetch for the swizzle to save.)
template <int REMAP>
__global__ __launch_bounds__(256)
void gemm_bf16_kernel(const ushort_t* __restrict__ A, const ushort_t* __restrict__ Bt,
                      const float* __restrict__ bias, void* __restrict__ dst,
                      int M, int Nn, int K, float qscale)
{
    __shared__ __align__(16) char As[8192];
    __shared__ __align__(16) char Bs[8192];
    const int tid = threadIdx.x;
    const int wv = tid >> 6, lane = tid & 63;
    const int l15 = lane & 15, lg = lane >> 4;
    const int m0 = blockIdx.y * 128, n0 = blockIdx.x * 128;
    const int wm = (wv >> 1) * 64, wn = (wv & 1) * 64;

    f32x4 acc[4][4] = {};
    const size_t ldb = (size_t)K * 2;   // bytes per row of A and Bt

    for (int k0 = 0; k0 < K; k0 += 32) {
        __syncthreads();
        #pragma unroll
        for (int q = 0; q < 2; ++q) {
            const int o = wv * 2048 + q * 1024 + lane * 16;
            const int sw = (o & 63) ^ ((((o >> 7) & 3)) << 4);
            const char* sa = (const char*)A + (size_t)(m0 + (o >> 6)) * ldb + k0 * 2 + sw;
            const char* sb = (const char*)Bt + (size_t)(n0 + (o >> 6)) * ldb + k0 * 2 + sw;
            GLOAD16(sa, As + wv * 2048 + q * 1024);
            GLOAD16(sb, Bs + wv * 2048 + q * 1024);
        }
        __syncthreads();
        bf16x8 af[4], bfr[4];
        #pragma unroll
        for (int i = 0; i < 4; ++i) {
            const int ra = wm + i * 16 + l15;
            af[i] = *(const bf16x8*)(As + ra * 64 + ((lg ^ ((ra >> 1) & 3)) << 4));
            const int rb = wn + i * 16 + l15;
            bfr[i] = *(const bf16x8*)(Bs + rb * 64 + ((lg ^ ((rb >> 1) & 3)) << 4));
        }
        #pragma unroll
        for (int i = 0; i < 4; ++i)
            #pragma unroll
            for (int j = 0; j < 4; ++j)
                acc[i][j] = __builtin_amdgcn_mfma_f32_16x16x32_bf16(af[i], bfr[j], acc[i][j], 0, 0, 0);
    }

    if (REMAP) {
        const int p = n0 / C2_;                       // constant per block
        const float os = (p == 0) ? qscale : 1.0f;    // *1.0f is exact identity
        ushort_t* D = (ushort_t*)dst + (size_t)p * ((size_t)BH_ * N_ * D2_);
        const int nb = n0 - p * C2_;
        #pragma unroll
        for (int i = 0; i < 4; ++i)
            #pragma unroll
            for (int r = 0; r < 4; ++r) {
                const int m = m0 + wm + i * 16 + lg * 4 + r;
                const int b = m >> 10, ns = m & 1023;
                #pragma unroll
                for (int j = 0; j < 4; ++j) {
                    const int n = nb + wn + j * 16 + l15;
                    const int h = n >> 7, d = n & 127;
                    D[(((size_t)(b * H_ + h)) * N_ + ns) * D2_ + d] = f2bf(acc[i][j][r] * os);
                }
            }
    } else {
        float* D = (float*)dst;
        #pragma unroll
        for (int i = 0; i < 4; ++i)
            #pragma unroll
            for (int r = 0; r < 4; ++r) {
                const int m = m0 + wm + i * 16 + lg * 4 + r;
                #pragma unroll
                for (int j = 0; j < 4; ++j) {
                    const int n = n0 + wn + j * 16 + l15;
                    D[(size_t)m * Nn + n] = acc[i][j][r] + bias[n];
                }
            }
    }
}

// ---------------- differential flash attention + LayerNorm, bf16 MFMA ----------------
// Block = 4 waves, 64 q-rows of one (b,h). S^T = K*Q^T so softmax rows are lane-local.
// Deterministic reg-staged dbuf. BYTE-EXACT R13 artifact (verified passing at
// absmax 0.0234375; six attempted inner-loop edits all corrupted — do not touch).
__global__ __launch_bounds__(256)
void attn_kernel(const ushort_t* __restrict__ qb, const ushort_t* __restrict__ kb,
                 const ushort_t* __restrict__ vt, const float* __restrict__ lamp,
                 const float* __restrict__ gamma, const float* __restrict__ beta,
                 ushort_t* __restrict__ Y)
{
    __shared__ __align__(16) char Ks[2][8192];
    __shared__ __align__(16) char Vs[2][8192];
    __shared__ __align__(16) ushort_t Ps[4][2][16 * 40];

    const int tid = threadIdx.x;
    const int wv = tid >> 6, lane = tid & 63;
    const int l15 = lane & 15, lg = lane >> 4;
    // XCD swizzle (bijection on [0,1536)): all 16 q-tiles of one (b,h) on one XCD
    const int swz = (blockIdx.x & 7) * 192 + (blockIdx.x >> 3);
    const int bh = swz >> 4;
    const int qt = swz & 15;

    const char* kbase = (const char*)kb + (size_t)bh * (N_ * D2_ * 2);
    const char* vbase = (const char*)vt + (size_t)bh * (N_ * D2_ * 2);

    // staging indices: K tile = 32 rows x 256B; V tile = 128 d-rows x 64B
    const int krow = tid >> 4, kcol = tid & 15;
    const int kg0 = tid * 16, kg1 = kg0 + 4096;
    const int ksw = (kcol ^ (krow & 7)) << 4;
    const int kw0 = krow * 256 + ksw;
    const int kw1 = (krow + 16) * 256 + ksw;
    const int vdr = tid >> 2, vpart = tid & 3;
    const size_t vg0 = (size_t)vdr * (N_ * 2) + vpart * 16;
    const size_t vg1 = (size_t)(vdr + 64) * (N_ * 2) + vpart * 16;
    const int vsw = (vpart ^ ((vdr >> 1) & 3)) << 4;
    const int vw0 = vdr * 64 + vsw;
    const int vw1 = (vdr + 64) * 64 + vsw;

    // Q fragments (B-operand); Q pre-scaled by D^-0.5*log2e at projection
    const int qrow = qt * 64 + wv * 16 + l15;
    const ushort_t* qptr = qb + (size_t)bh * N_ * D2_ + (size_t)qrow * D2_;
    bf16x8 Qf[4];
    #pragma unroll
    for (int c = 0; c < 4; ++c)
        Qf[c] = *(const bf16x8*)(qptr + c * 32 + lg * 8);

    f32x4 O1[8] = {}, O2[8] = {};
    float l1p = 0.f, l2p = 0.f;

    // prologue: stage tile 0 through registers
    {
        uint4 a = *(const uint4*)(kbase + kg0);
        uint4 b = *(const uint4*)(kbase + kg1);
        uint4 c = *(const uint4*)(vbase + vg0);
        uint4 d = *(const uint4*)(vbase + vg1);
        *(uint4*)(Ks[0] + kw0) = a; *(uint4*)(Ks[0] + kw1) = b;
        *(uint4*)(Vs[0] + vw0) = c; *(uint4*)(Vs[0] + vw1) = d;
    }
    __syncthreads();
    int cur = 0;

    for (int t = 0; t < 32; ++t) {
        // issue next tile's global loads early (latency hides under compute)
        uint4 nk0, nk1, nv0, nv1;
        if (t < 31) {
            nk0 = *(const uint4*)(kbase + (t + 1) * 8192 + kg0);
            nk1 = *(const uint4*)(kbase + (t + 1) * 8192 + kg1);
            nv0 = *(const uint4*)(vbase + vg0 + (t + 1) * 64);
            nv1 = *(const uint4*)(vbase + vg1 + (t + 1) * 64);
        }

        const char* Kc = Ks[cur];
        const char* Vc = Vs[cur];

        // S^T = K * Q^T ; split1 = d 0..63 (chunks 0,1), split2 = d 64..127
        f32x4 s1[2], s2[2];
        #pragma unroll
        for (int u = 0; u < 2; ++u) {
            const int row = u * 16 + l15;
            const char* kp = Kc + row * 256;
            bf16x8 k0 = *(const bf16x8*)(kp + (((0  + lg) ^ (row & 7)) << 4));
            bf16x8 k1 = *(const bf16x8*)(kp + (((4  + lg) ^ (row & 7)) << 4));
            bf16x8 k2 = *(const bf16x8*)(kp + (((8  + lg) ^ (row & 7)) << 4));
            bf16x8 k3 = *(const bf16x8*)(kp + (((12 + lg) ^ (row & 7)) << 4));
            f32x4 z = {0.f, 0.f, 0.f, 0.f};
            s1[u] = __builtin_amdgcn_mfma_f32_16x16x32_bf16(k0, Qf[0], z, 0, 0, 0);
            s1[u] = __builtin_amdgcn_mfma_f32_16x16x32_bf16(k1, Qf[1], s1[u], 0, 0, 0);
            s2[u] = __builtin_amdgcn_mfma_f32_16x16x32_bf16(k2, Qf[2], z, 0, 0, 0);
            s2[u] = __builtin_amdgcn_mfma_f32_16x16x32_bf16(k3, Qf[3], s2[u], 0, 0, 0);
        }

        // exp2 (scores already in log2 units) + HW packed bf16 convert
        float lp1 = 0.f, lp2 = 0.f;
        #pragma unroll
        for (int u = 0; u < 2; ++u) {
            const uint_t base = (uint_t)(l15 * 40 + u * 16 + lg * 4) >> 1;
            float a0 = exp2f(s1[u][0]), a1 = exp2f(s1[u][1]);
            float a2 = exp2f(s1[u][2]), a3 = exp2f(s1[u][3]);
            lp1 += (a0 + a1) + (a2 + a3);
            ((uint_t*)Ps[wv][0])[base]     = cvtpk(a0, a1);
            ((uint_t*)Ps[wv][0])[base + 1] = cvtpk(a2, a3);
            float b0 = exp2f(s2[u][0]), b1 = exp2f(s2[u][1]);
            float b2 = exp2f(s2[u][2]), b3 = exp2f(s2[u][3]);
            lp2 += (b0 + b1) + (b2 + b3);
            ((uint_t*)Ps[wv][1])[base]     = cvtpk(b0, b1);
            ((uint_t*)Ps[wv][1])[base + 1] = cvtpk(b2, b3);
        }
        l1p += lp1; l2p += lp2;

        bf16x8 pa1 = *(const bf16x8*)&Ps[wv][0][l15 * 40 + lg * 8];
        bf16x8 pa2 = *(const bf16x8*)&Ps[wv][1][l15 * 40 + lg * 8];

        #pragma unroll
        for (int c = 0; c < 8; ++c) {
            const int dr = c * 16 + l15;
            bf16x8 vf = *(const bf16x8*)(Vc + dr * 64 + ((lg ^ ((dr >> 1) & 3)) << 4));
            O1[c] = __builtin_amdgcn_mfma_f32_16x16x32_bf16(pa1, vf, O1[c], 0, 0, 0);
            O2[c] = __builtin_amdgcn_mfma_f32_16x16x32_bf16(pa2, vf, O2[c], 0, 0, 0);
        }

        // write next tile into the other buffer (no aliasing with this tile's reads)
        if (t < 31) {
            char* Kn = Ks[cur ^ 1];
            char* Vn = Vs[cur ^ 1];
            *(uint4*)(Kn + kw0) = nk0; *(uint4*)(Kn + kw1) = nk1;
            *(uint4*)(Vn + vw0) = nv0; *(uint4*)(Vn + vw1) = nv1;
        }
        __syncthreads();
        cur ^= 1;
    }

    // ---- epilogue: normalize, differential combine, LayerNorm, write Y ----
    float l1 = l1p + __shfl_xor(l1p, 16); l1 += __shfl_xor(l1, 32);
    float l2 = l2p + __shfl_xor(l2p, 16); l2 += __shfl_xor(l2, 32);
    const float lam = lamp[0];
    float i1[4], i2[4];
    #pragma unroll
    for (int r = 0; r < 4; ++r) {
        i1[r] = 1.f / __shfl(l1, lg * 4 + r);
        i2[r] = lam / __shfl(l2, lg * 4 + r);
    }
    float su[4] = {0.f, 0.f, 0.f, 0.f}, sq[4] = {0.f, 0.f, 0.f, 0.f};
    float ov[8][4];
    #pragma unroll
    for (int c = 0; c < 8; ++c)
        #pragma unroll
        for (int r = 0; r < 4; ++r) {
            const float v = O1[c][r] * i1[r] - O2[c][r] * i2[r];
            ov[c][r] = v; su[r] += v; sq[r] += v * v;
        }
    #pragma unroll
    for (int r = 0; r < 4; ++r) {
        #pragma unroll
        for (int msk = 1; msk <= 8; msk <<= 1) {
            su[r] += __shfl_xor(su[r], msk);
            sq[r] += __shfl_xor(sq[r], msk);
        }
    }
    float gv[8], bv[8];
    #pragma unroll
    for (int c = 0; c < 8; ++c) { gv[c] = gamma[c * 16 + l15]; bv[c] = beta[c * 16 + l15]; }

    const int b = bh / H_, h = bh - (bh / H_) * H_;
    #pragma unroll
    for (int r = 0; r < 4; ++r) {
        const float mu = su[r] * (1.f / 128.f);
        const float var = sq[r] * (1.f / 128.f) - mu * mu;
        const float rstd = rsqrtf(var + EPS_);
        const int n = qt * 64 + wv * 16 + lg * 4 + r;
        ushort_t* yrow = Y + ((size_t)(b * N_ + n)) * C2_ + h * D2_;
        #pragma unroll
        for (int c = 0; c < 8; ++c) {
            const int d = c * 16 + l15;
            const float val = ((ov[c][r] - mu) * rstd * gv[c] + bv[c]) * OUT_SCALE;
            yrow[d] = f2bf(val);
        }
    }
}

extern "C" void kernel_launch(void* const* d_in, const int* in_sizes, int n_in,
                              void* d_out, int out_size, void* d_ws, size_t ws_size,
                              hipStream_t stream) {
    const float* x     = (const float*)d_in[0];
    const float* Wq    = (const float*)d_in[1];
    const float* Wk    = (const float*)d_in[2];
    const float* Wv    = (const float*)d_in[3];
    const float* lam   = (const float*)d_in[4];
    const float* gamma = (const float*)d_in[5];
    const float* beta  = (const float*)d_in[6];
    const float* Wp    = (const float*)d_in[7];
    const float* bp    = (const float*)d_in[8];
    float* out = (float*)d_out;

    // workspace layout (bytes)
    char* w = (char*)d_ws;
    ushort_t* xb  = (ushort_t*)w;                 w += (size_t)B_ * N_ * C_ * 2;        // 12.6MB
    ushort_t* wqt = (ushort_t*)w;                 w += (size_t)C2_ * C_ * 2;            // 2.36MB (x3, consecutive)
    ushort_t* wkt = (ushort_t*)w;                 w += (size_t)C2_ * C_ * 2;
    ushort_t* wvt = (ushort_t*)w;                 w += (size_t)C2_ * C_ * 2;
    ushort_t* wpt = (ushort_t*)w;                 w += (size_t)C_ * C2_ * 2;
    ushort_t* qbuf = (ushort_t*)w;                w += (size_t)BH_ * N_ * D2_ * 2;      // 25.2MB (q,k,v consecutive)
    ushort_t* kbuf = (ushort_t*)w;                w += (size_t)BH_ * N_ * D2_ * 2;
    ushort_t* vbuf = (ushort_t*)w;                w += (size_t)BH_ * N_ * D2_ * 2;
    ushort_t* vtb  = (ushort_t*)w;                w += (size_t)BH_ * N_ * D2_ * 2;
    ushort_t* Yb   = (ushort_t*)w;                w += (size_t)B_ * N_ * C2_ * 2;       // 25.2MB

    const int M = B_ * N_;   // 8192

    // convert x to bf16
    cvt_bf16_kernel<<<2048, 256, 0, stream>>>(x, xb, (B_ * N_ * C_) / 4);
    // all four weight transposes in one launch
    transpose_cvt4_kernel<<<dim3(48, 48, 4), 256, 0, stream>>>(Wq, Wk, Wv, Wp,
                                                               wqt, wkt, wvt, wpt);

    // fused QKV projection: one GEMM over [Wq;Wk;Wv] (N=4608); Q pre-scaled
    {
        dim3 grid((3 * C2_) / 128, M / 128);
        gemm_bf16_kernel<1><<<grid, 256, 0, stream>>>(xb, wqt, nullptr, qbuf,
                                                      M, 3 * C2_, C_, SCALE_LOG2);
    }
    (void)kbuf;
    // V -> V^T per head
    transpose_v_kernel<<<dim3(D2_ / 64, N_ / 64, BH_), 256, 0, stream>>>(vbuf, vtb);

    // differential attention + LN -> Y (B,N,2C) bf16
    attn_kernel<<<dim3(BH_ * (N_ / 64)), 256, 0, stream>>>(qbuf, kbuf, vtb, lam, gamma, beta, Yb);

    // output projection: out = Y @ Wp + bp (f32)
    {
        dim3 grid(C_ / 128, M / 128);
        gemm_bf16_kernel<0><<<grid, 256, 0, stream>>>(Yb, wpt, bp, out, M, C_, C2_, 1.0f);
    }
}